// Round 3
// baseline (343.204 us; speedup 1.0000x reference)
//
#include <hip/hip_runtime.h>
#include <hip/hip_fp16.h>

namespace {

constexpr int kFeat = 32;
constexpr int kNA = 64;
constexpr int kNE = 32;
constexpr int kGridElems = kFeat * kNA * kNE;   // 65536
constexpr int kPoleElems = kFeat * 2;           // 64
constexpr int kCols = kNA * kNE;                // 2048 grid columns
constexpr int kColS = kCols;                    // pole-south column index
constexpr int kColN = kCols + 1;                // pole-north column index
constexpr int kTotCols = kCols + 2;             // 2050
constexpr int kLdsHalfs = kTotCols * kFeat;     // 65600 halfs = 128.125 KiB
constexpr int kLdsVec = kLdsHalfs / 8;          // 8200 uint4s (exact)

constexpr float kPi  = 3.14159265358979323846f;
constexpr float kPi2 = 1.57079632679489661923f;
constexpr float kOmegaAz = 0.09817477042468103f;   // 2*pi/64
constexpr float kOmegaEl = 0.09519977738150889f;   // pi/33
constexpr float kInvOmegaAz = 10.18591635788130f;  // 64/(2*pi)
constexpr float kInvOmegaEl = 10.50422624406509f;  // 33/pi
constexpr float kInvSinAz = 10.20229703f;          // 1/sin(2*pi/64)
constexpr float kInvSinEl = 10.52010966f;          // 1/sin(pi/33)

// Prepass: grid [F][A][E] fp32 -> gt [A*E + 2][F] fp16 (a feature column is
// one contiguous 64B cache line); poles appended as columns 2048/2049.
__global__ __launch_bounds__(256) void transpose_grid_h(
    const float* __restrict__ g, const float* __restrict__ poles,
    __half* __restrict__ gt) {
  int idx = blockIdx.x * 256 + threadIdx.x;
  if (idx < kGridElems) {
    int f = idx >> 11;       // / (NA*NE)
    int ae = idx & 2047;     // a*NE + e
    gt[ae * kFeat + f] = __float2half(g[idx]);
  }
  if (idx < kPoleElems) {
    int f = idx >> 1;
    int p = idx & 1;
    gt[(kCols + p) * kFeat + f] = __float2half(poles[idx]);
  }
}

struct PointSetup {
  int col_bl, col_br, col_tl, col_tr;
  float a1, a2, b1, b2;
};

__device__ __forceinline__ PointSetup setup_point(float az, float el) {
  PointSetup s;
  // azimuth bucket: ar = smallest k with tick_az[k] >= az; ticks at -pi + k*omega
  float ta = (az + kPi) * kInvOmegaAz;
  int ar0 = (int)ceilf(ta);
  int al = ar0 - 1;
  int ar = (ar0 >= kNA) ? 0 : ar0;
  if (al < 0) al = kNA - 1;
  float theta_a = az - (-kPi + (float)al * kOmegaAz);
  float w1a = __sinf(kOmegaAz - theta_a) * kInvSinAz;
  float w2a = __sinf(theta_a) * kInvSinAz;

  // elevation: er = searchsorted(interior ticks at -pi/2 + (k+1)*omega_el)
  float ue = (el + kPi2) * kInvOmegaEl;
  int er = (int)ceilf(ue) - 1;
  er = min(max(er, 0), kNE);
  bool south = (er == 0);
  bool north = (er == kNE);
  int eil = min(max(er - 1, 0), kNE - 1);
  int eir = min(er, kNE - 1);
  float base = south ? -kPi2 : (-kPi2 + (float)(eil + 1) * kOmegaEl);
  float theta_e = el - base;
  float w1e = __sinf(kOmegaEl - theta_e) * kInvSinEl;
  float w2e = __sinf(theta_e) * kInvSinEl;

  s.col_bl = al * kNE + eil;
  s.col_br = ar * kNE + eil;
  s.col_tl = al * kNE + eir;
  s.col_tr = ar * kNE + eir;
  s.a1 = w1e * w1a; s.a2 = w1e * w2a;
  s.b1 = w2e * w1a; s.b2 = w2e * w2a;
  // Pole redirect: exact pole value via two identical half-weight columns
  // (NORMALIZED=False, weights need not sum to 1).
  if (south) {
    s.col_bl = kColS; s.col_br = kColS;
    s.a1 = 0.5f * w1e; s.a2 = s.a1;
  }
  if (north) {
    s.col_tl = kColN; s.col_tr = kColN;
    s.b1 = 0.5f * w2e; s.b2 = s.b1;
  }
  return s;
}

__device__ __forceinline__ void compute_store(
    const PointSetup& s, const uint4& blu, const uint4& bru,
    const uint4& tlu, const uint4& tru, int i, int j,
    float* __restrict__ out, size_t sn) {
  union H8 { uint4 u; __half2 h[4]; };
  H8 bl, br, tl, tr;
  bl.u = blu; br.u = bru; tl.u = tlu; tr.u = tru;
  float acc[8];
#pragma unroll
  for (int q = 0; q < 4; ++q) {
    float2 vbl = __half22float2(bl.h[q]);
    float2 vbr = __half22float2(br.h[q]);
    float2 vtl = __half22float2(tl.h[q]);
    float2 vtr = __half22float2(tr.h[q]);
    acc[2 * q + 0] = s.a1 * vbl.x + s.a2 * vbr.x + s.b1 * vtl.x + s.b2 * vtr.x;
    acc[2 * q + 1] = s.a1 * vbl.y + s.a2 * vbr.y + s.b1 * vtl.y + s.b2 * vtr.y;
  }
  float* o = out + (size_t)(8 * j) * sn + i;
#pragma unroll
  for (int k = 0; k < 8; ++k) o[(size_t)k * sn] = acc[k];
}

// LDS-resident table: one 1024-thread block per CU holds the whole 128.125 KiB
// fp16 table in LDS (16 waves/CU = 4/SIMD). Gathers become ds_read_b128 --
// a point's 4 lanes read one contiguous 64B column (16 banks, selected by
// column parity; 4 points/16-lane phase average a 2:2 parity split = ~2-way
// aliasing, which is free). This takes the 16-distinct-line random gathers
// off the per-CU vector-memory pipe; VMEM now carries only the coalesced
// stores (4 full 64B lines/instr) and prefetched pts loads.
// Chunks are 64-slot aligned so each wave covers 16 consecutive points
// (aligned full-line store segments, as before).
__global__ __launch_bounds__(1024) void interp_lds(
    const float* __restrict__ pts, const __half* __restrict__ gt,
    float* __restrict__ out, int n, long long chunk) {
  __shared__ __half lds[kLdsHalfs];
  {
    const uint4* src = (const uint4*)gt;
    uint4* dst = (uint4*)lds;
    for (int t = threadIdx.x; t < kLdsVec; t += 1024) dst[t] = src[t];
  }
  __syncthreads();

  const long long nslots = 4LL * n;
  long long base = (long long)blockIdx.x * chunk;
  long long end = base + chunk;
  if (end > nslots) end = nslots;
  const size_t sn = (size_t)n;

  long long slot = base + threadIdx.x;
  float az = 0.f, el = 0.f;
  if (slot < end) {
    int i = (int)(slot >> 2);
    az = pts[i];
    el = pts[n + i];
  }
  while (slot < end) {
    const long long next = slot + 1024;
    const int i = (int)(slot >> 2);
    const int j = (int)(slot & 3);
    PointSetup s = setup_point(az, el);
    const int off = j * 8;
    uint4 bl = *(const uint4*)(lds + s.col_bl * kFeat + off);
    uint4 br = *(const uint4*)(lds + s.col_br * kFeat + off);
    uint4 tl = *(const uint4*)(lds + s.col_tl * kFeat + off);
    uint4 tr = *(const uint4*)(lds + s.col_tr * kFeat + off);
    if (next < end) {  // prefetch next iteration's point while LDS reads fly
      int i2 = (int)(next >> 2);
      az = pts[i2];
      el = pts[n + i2];
    }
    compute_store(s, bl, br, tl, tr, i, j, out, sn);
    slot = next;
  }
}

// Fallback if the workspace is too small for the transposed fp16 grid:
// gather directly from the [F][A][E] layout (scalar strided loads).
__global__ __launch_bounds__(256) void interp_d(
    const float* __restrict__ pts, const float* __restrict__ g,
    const float* __restrict__ poles, float* __restrict__ out, int n) {
  int i = blockIdx.x * 256 + threadIdx.x;
  if (i >= n) return;
  float az = pts[i];
  float el = pts[n + i];
  PointSetup s = setup_point(az, el);

  float a1 = s.a1, a2 = s.a2, b1 = s.b1, b2 = s.b2;
  float pw0 = 0.0f, pw1 = 0.0f;
  if (s.col_bl == kColS) { pw0 = a1 + a2; a1 = 0.0f; a2 = 0.0f; }
  if (s.col_tl == kColN) { pw1 = b1 + b2; b1 = 0.0f; b2 = 0.0f; }

  const float* gbl = g + (s.col_bl < kCols ? s.col_bl : 0);
  const float* gbr = g + (s.col_br < kCols ? s.col_br : 0);
  const float* gtl = g + (s.col_tl < kCols ? s.col_tl : 0);
  const float* gtr = g + (s.col_tr < kCols ? s.col_tr : 0);
  size_t sn = (size_t)n;
#pragma unroll 8
  for (int f = 0; f < kFeat; ++f) {
    float v = a1 * gbl[f * kCols] + a2 * gbr[f * kCols]
            + b1 * gtl[f * kCols] + b2 * gtr[f * kCols]
            + pw0 * poles[f * 2 + 0] + pw1 * poles[f * 2 + 1];
    out[(size_t)f * sn + i] = v;
  }
}

}  // namespace

extern "C" void kernel_launch(void* const* d_in, const int* in_sizes, int n_in,
                              void* d_out, int out_size, void* d_ws, size_t ws_size,
                              hipStream_t stream) {
  (void)n_in; (void)out_size;
  const float* pts   = (const float*)d_in[0];
  const float* grid  = (const float*)d_in[1];
  const float* poles = (const float*)d_in[2];
  float* out = (float*)d_out;
  int n = in_sizes[0] / 2;

  size_t need = (size_t)(kTotCols * kFeat) * sizeof(__half);
  if (ws_size >= need) {
    __half* gt = (__half*)d_ws;
    transpose_grid_h<<<(kGridElems + 255) / 256, 256, 0, stream>>>(grid, poles, gt);
    const long long slots = 4LL * n;
    const int blocks = 256;  // one 128KiB-LDS block per CU
    // 64-aligned chunk keeps wave->16-point alignment (full-line segments)
    long long chunk =
        ((slots + (long long)blocks * 64 - 1) / ((long long)blocks * 64)) * 64;
    interp_lds<<<blocks, 1024, 0, stream>>>(pts, gt, out, n, chunk);
  } else {
    int blocks = (n + 255) / 256;
    interp_d<<<blocks, 256, 0, stream>>>(pts, grid, poles, out, n);
  }
}

// Round 4
// 292.328 us; speedup vs baseline: 1.1740x; 1.1740x over previous
//
#include <hip/hip_runtime.h>
#include <hip/hip_fp16.h>

namespace {

constexpr int kFeat = 32;
constexpr int kNA = 64;
constexpr int kNE = 32;
constexpr int kGridElems = kFeat * kNA * kNE;   // 65536
constexpr int kPoleElems = kFeat * 2;           // 64
constexpr int kCols = kNA * kNE;                // 2048 grid columns
constexpr int kColS = kCols;                    // pole-south column index
constexpr int kColN = kCols + 1;                // pole-north column index
constexpr int kTotCols = kCols + 2;             // 2050

constexpr float kPi  = 3.14159265358979323846f;
constexpr float kPi2 = 1.57079632679489661923f;
constexpr float kOmegaAz = 0.09817477042468103f;   // 2*pi/64
constexpr float kOmegaEl = 0.09519977738150889f;   // pi/33
constexpr float kInvOmegaAz = 10.18591635788130f;  // 64/(2*pi)
constexpr float kInvOmegaEl = 10.50422624406509f;  // 33/pi
constexpr float kInvSinAz = 10.20229703f;          // 1/sin(2*pi/64)
constexpr float kInvSinEl = 10.52010966f;          // 1/sin(pi/33)

// Prepass: grid [F][A][E] fp32 -> gt [A*E + 2][F] fp16 (a feature column is
// one contiguous 64B cache line); poles appended as columns 2048/2049.
__global__ __launch_bounds__(256) void transpose_grid_h(
    const float* __restrict__ g, const float* __restrict__ poles,
    __half* __restrict__ gt) {
  int idx = blockIdx.x * 256 + threadIdx.x;
  if (idx < kGridElems) {
    int f = idx >> 11;       // / (NA*NE)
    int ae = idx & 2047;     // a*NE + e
    gt[ae * kFeat + f] = __float2half(g[idx]);
  }
  if (idx < kPoleElems) {
    int f = idx >> 1;
    int p = idx & 1;
    gt[(kCols + p) * kFeat + f] = __float2half(poles[idx]);
  }
}

struct PointSetup {
  int col_bl, col_br, col_tl, col_tr;
  float a1, a2, b1, b2;
};

__device__ __forceinline__ PointSetup setup_point(float az, float el) {
  PointSetup s;
  // azimuth bucket: ar = smallest k with tick_az[k] >= az; ticks at -pi + k*omega
  float ta = (az + kPi) * kInvOmegaAz;
  int ar0 = (int)ceilf(ta);
  int al = ar0 - 1;
  int ar = (ar0 >= kNA) ? 0 : ar0;
  if (al < 0) al = kNA - 1;
  float theta_a = az - (-kPi + (float)al * kOmegaAz);
  float w1a = __sinf(kOmegaAz - theta_a) * kInvSinAz;
  float w2a = __sinf(theta_a) * kInvSinAz;

  // elevation: er = searchsorted(interior ticks at -pi/2 + (k+1)*omega_el)
  float ue = (el + kPi2) * kInvOmegaEl;
  int er = (int)ceilf(ue) - 1;
  er = min(max(er, 0), kNE);
  bool south = (er == 0);
  bool north = (er == kNE);
  int eil = min(max(er - 1, 0), kNE - 1);
  int eir = min(er, kNE - 1);
  float base = south ? -kPi2 : (-kPi2 + (float)(eil + 1) * kOmegaEl);
  float theta_e = el - base;
  float w1e = __sinf(kOmegaEl - theta_e) * kInvSinEl;
  float w2e = __sinf(theta_e) * kInvSinEl;

  s.col_bl = al * kNE + eil;
  s.col_br = ar * kNE + eil;
  s.col_tl = al * kNE + eir;
  s.col_tr = ar * kNE + eir;
  s.a1 = w1e * w1a; s.a2 = w1e * w2a;
  s.b1 = w2e * w1a; s.b2 = w2e * w2a;
  // Pole redirect: exact pole value via two identical half-weight columns
  // (NORMALIZED=False, weights need not sum to 1).
  if (south) {
    s.col_bl = kColS; s.col_br = kColS;
    s.a1 = 0.5f * w1e; s.a2 = s.a1;
  }
  if (north) {
    s.col_tl = kColN; s.col_tr = kColN;
    s.b1 = 0.5f * w2e; s.b2 = s.b1;
  }
  return s;
}

// Tiled interp: block of 256 threads owns kTile=256 consecutive points.
// Compute phase keeps the proven gather scheme (4 lanes/point, lane j loads
// the 16B fp16 half-quad j of each of the 4 columns; a gather instr covers 16
// whole 64B columns), but results go into a [32][256] f32 LDS staging tile
// instead of scattered 64B global segments. Flush phase then writes the tile
// with 64-lane dwordx4 stores: each store instruction emits 1 KB of fully
// contiguous, 128B-line-complete output (no read-for-ownership on 128B L2
// lines, 16x longer HBM bursts, 4x fewer store instructions). Store-stream
// granularity is the one variable changed vs the ~150us R0/R2/R3 plateau.
constexpr int kTile = 256;               // points per block
constexpr int kTileFloats = kFeat * kTile;   // 8192 floats = 32 KiB LDS

__global__ __launch_bounds__(256) void interp_t(
    const float* __restrict__ pts, const __half* __restrict__ gt,
    float* __restrict__ out, int n) {
  __shared__ float tile[kTileFloats];    // [feat][point], row-major
  const int base = blockIdx.x * kTile;
  const int rem = min(kTile, n - base);
  const size_t sn = (size_t)n;
  const int t = threadIdx.x;

  // ---- compute phase: 4 local slots per thread (slots L = t, t+256, ...) ----
  // Hoist the pts loads for all 4 slots so 8 loads are in flight at once.
  int   pidx[4];
  float azv[4], elv[4];
#pragma unroll
  for (int c = 0; c < 4; ++c) {
    int L = t + 256 * c;
    int p = L >> 2;
    pidx[c] = p;
    if (p < rem) {
      int i = base + p;
      azv[c] = pts[i];
      elv[c] = pts[n + i];
    } else {
      azv[c] = 0.f; elv[c] = 0.f;
    }
  }

#pragma unroll
  for (int c = 0; c < 4; ++c) {
    int L = t + 256 * c;
    int p = pidx[c];
    int j = L & 3;
    if (p < rem) {
      PointSetup s = setup_point(azv[c], elv[c]);
      union H8 { uint4 u; __half2 h[4]; };
      H8 bl, br, tl, tr;
      const int off = j * 8;
      bl.u = *(const uint4*)(gt + s.col_bl * kFeat + off);
      br.u = *(const uint4*)(gt + s.col_br * kFeat + off);
      tl.u = *(const uint4*)(gt + s.col_tl * kFeat + off);
      tr.u = *(const uint4*)(gt + s.col_tr * kFeat + off);

      float* dst = tile + (8 * j) * kTile + p;   // rows 8j..8j+7, column p
#pragma unroll
      for (int q = 0; q < 4; ++q) {
        float2 vbl = __half22float2(bl.h[q]);
        float2 vbr = __half22float2(br.h[q]);
        float2 vtl = __half22float2(tl.h[q]);
        float2 vtr = __half22float2(tr.h[q]);
        dst[(2 * q + 0) * kTile] =
            s.a1 * vbl.x + s.a2 * vbr.x + s.b1 * vtl.x + s.b2 * vtr.x;
        dst[(2 * q + 1) * kTile] =
            s.a1 * vbl.y + s.a2 * vbr.y + s.b1 * vtl.y + s.b2 * vtr.y;
      }
    }
  }

  __syncthreads();

  // ---- flush phase: LDS tile -> global, 1 KB contiguous per wave-store ----
  // tile is [32][256] f32 = 2048 uint4, linear index u; row = u>>6 (64 uint4
  // per row), col = u&63. Wave lanes cover 64 consecutive u = one full row
  // per store instruction (1 KB contiguous, rows w, w+4, ..., w+28).
  if (rem == kTile) {
    const uint4* src = (const uint4*)tile;
#pragma unroll
    for (int r = 0; r < 8; ++r) {
      int u = t + 256 * r;
      int row = u >> 6;
      int col = u & 63;
      *(uint4*)(out + (size_t)row * sn + base + 4 * col) = src[u];
    }
  } else {
    // last partial tile: guarded element stores
    for (int r = 0; r < 8; ++r) {
      int u = t + 256 * r;
      int row = u >> 6;
      int col4 = (u & 63) * 4;
      if (col4 < rem) {
        int m = min(4, rem - col4);
        const float* s4 = tile + row * kTile + col4;
        float* o = out + (size_t)row * sn + base + col4;
        for (int e = 0; e < m; ++e) o[e] = s4[e];
      }
    }
  }
}

// Fallback if the workspace is too small for the transposed fp16 grid:
// gather directly from the [F][A][E] layout (scalar strided loads).
__global__ __launch_bounds__(256) void interp_d(
    const float* __restrict__ pts, const float* __restrict__ g,
    const float* __restrict__ poles, float* __restrict__ out, int n) {
  int i = blockIdx.x * 256 + threadIdx.x;
  if (i >= n) return;
  float az = pts[i];
  float el = pts[n + i];
  PointSetup s = setup_point(az, el);

  float a1 = s.a1, a2 = s.a2, b1 = s.b1, b2 = s.b2;
  float pw0 = 0.0f, pw1 = 0.0f;
  if (s.col_bl == kColS) { pw0 = a1 + a2; a1 = 0.0f; a2 = 0.0f; }
  if (s.col_tl == kColN) { pw1 = b1 + b2; b1 = 0.0f; b2 = 0.0f; }

  const float* gbl = g + (s.col_bl < kCols ? s.col_bl : 0);
  const float* gbr = g + (s.col_br < kCols ? s.col_br : 0);
  const float* gtl = g + (s.col_tl < kCols ? s.col_tl : 0);
  const float* gtr = g + (s.col_tr < kCols ? s.col_tr : 0);
  size_t sn = (size_t)n;
#pragma unroll 8
  for (int f = 0; f < kFeat; ++f) {
    float v = a1 * gbl[f * kCols] + a2 * gbr[f * kCols]
            + b1 * gtl[f * kCols] + b2 * gtr[f * kCols]
            + pw0 * poles[f * 2 + 0] + pw1 * poles[f * 2 + 1];
    out[(size_t)f * sn + i] = v;
  }
}

}  // namespace

extern "C" void kernel_launch(void* const* d_in, const int* in_sizes, int n_in,
                              void* d_out, int out_size, void* d_ws, size_t ws_size,
                              hipStream_t stream) {
  (void)n_in; (void)out_size;
  const float* pts   = (const float*)d_in[0];
  const float* grid  = (const float*)d_in[1];
  const float* poles = (const float*)d_in[2];
  float* out = (float*)d_out;
  int n = in_sizes[0] / 2;

  size_t need = (size_t)(kTotCols * kFeat) * sizeof(__half);
  if (ws_size >= need) {
    __half* gt = (__half*)d_ws;
    transpose_grid_h<<<(kGridElems + 255) / 256, 256, 0, stream>>>(grid, poles, gt);
    int blocks = (n + kTile - 1) / kTile;
    interp_t<<<blocks, 256, 0, stream>>>(pts, gt, out, n);
  } else {
    int blocks = (n + 255) / 256;
    interp_d<<<blocks, 256, 0, stream>>>(pts, grid, poles, out, n);
  }
}